// Round 19
// baseline (46.147 us; speedup 1.0000x reference)
//
#include <hip/hip_runtime.h>
#include <hip/hip_bf16.h>
#include <float.h>

// RigidityLoss: M=16384 gathered points, brute-force KNN (K=8) + loss.
// R18 = R13 + PAIR-MIN unpack: raw dv min-reduced across the 2 tiles of a
// pair in f32 BEFORE packing. Selection-EQUIVALENT to R13 (bins kept top-1
// over 32 cands; pair-min preserves the bin min; exact-f32 argmin within
// the winning pair recovers the bin argmin). Unpack: 3 VALU/elem/2 tiles
// vs 4 (-25% of dominant cost). Only 2 concurrent dv buffers (no R15 VGPR
// blowup); merge adds one PARALLEL c4 load per round (no serial chain).

#define MPTS 16384
#define KNN  8
#define CDIM 16
#define LAMW 0.1f
#define EPSV 1e-6f

#define ROWS   32              // rows per block (one 32x32 MFMA row-tile)
#define NSPLIT 8               // waves per block = candidate splits
#define CSPL   1024            // candidates per split (half / 8 waves)
#define NT     (CSPL/32)       // 32 MFMA tiles per wave
#define BSTR   257             // padded LDS bin-row stride (words)

#define MED3 __builtin_amdgcn_fmed3f
typedef __attribute__((ext_vector_type(8)))  _Float16 f16x8;
typedef __attribute__((ext_vector_type(16))) float    f32x16;

__global__ __launch_bounds__(256) void k_gather(
    const float* __restrict__ canon, const float* __restrict__ trans,
    const int* __restrict__ indice, float4* __restrict__ c4,
    _Float16* __restrict__ bf16b, _Float16* __restrict__ af16b,
    float* __restrict__ acc)
{
    int t = blockIdx.x * 256 + threadIdx.x;
    if (t == 0) { acc[0] = 0.f; acc[1] = 0.f; }
    if (t < MPTS) {
        int j = indice[t];
        float x = canon[3*j+0] + trans[3*j+0];
        float y = canon[3*j+1] + trans[3*j+1];
        float z = canon[3*j+2] + trans[3*j+2];
        float sq = fmaf(x, x, fmaf(y, y, z*z));
        c4[t] = make_float4(-2.f*x, -2.f*y, -2.f*z, sq);   // exact f32 blob
        f16x8 aa = {};
        aa[0] = (_Float16)(-2.f*x); aa[1] = (_Float16)(-2.f*y);
        aa[2] = (_Float16)(-2.f*z); aa[3] = (_Float16)1.0f;
        *(f16x8*)(af16b + (size_t)t*8) = aa;
        f16x8 bb = {};
        bb[0] = (_Float16)x; bb[1] = (_Float16)y; bb[2] = (_Float16)z;
        bb[3] = (_Float16)sq;
        *(f16x8*)(bf16b + (size_t)t*8) = bb;
    }
}

__global__ __launch_bounds__(512, 4) void k_knn(
    const _Float16* __restrict__ bf16b, const _Float16* __restrict__ af16b,
    float* __restrict__ keys)
{
    __shared__ float bins[ROWS * BSTR];      // 32.9 KB

    const int tid  = threadIdx.x;
    const int lane = tid & 63;
    const int wv   = tid >> 6;               // wave = candidate split 0..7
    const int half = blockIdx.x & 1;
    const int rowbase = (blockIdx.x >> 1) * ROWS;
    const int cls  = lane & 31;
    const int cbeg = half * (MPTS/2) + wv * CSPL;

    // A fragment: lane l<32 -> row (rowbase+l), k=0..7; lanes>=32 (k=8..15) zero.
    f16x8 afrag = *(const f16x8*)(af16b + (size_t)(rowbase + cls) * 8);
    if (lane >= 32) { f16x8 zz = {}; afrag = zz; }
    f32x16 zero16 = {};

    const _Float16* bptr  = bf16b + (size_t)(cbeg + cls) * 8;
    const unsigned  HMASK = 0xFFFFC000u;
    const unsigned  ivb   = (unsigned)(cbeg + cls);

    // 16 row-states (g -> row (g&3)+8*(g>>2)+4*(lane>>5)), top-1 each
    float e0=FLT_MAX,e1=FLT_MAX,e2=FLT_MAX,e3=FLT_MAX;
    float e4=FLT_MAX,e5=FLT_MAX,e6=FLT_MAX,e7=FLT_MAX;
    float e8=FLT_MAX,e9=FLT_MAX,e10=FLT_MAX,e11=FLT_MAX;
    float e12=FLT_MAX,e13=FLT_MAX,e14=FLT_MAX,e15=FLT_MAX;

#define LD(T) (*(const f16x8*)(bptr + (size_t)(((T) & (NT-1)) * 256)))
    // pair-min: min(dvA,dvB) in f32, pack once; payload = pair base index
    // {j0, j0+32}, resolved exactly in the merge kernel.
#define DOPAIR(PA, PB, T)                                                      \
    {                                                                          \
        f32x16 dvA = __builtin_amdgcn_mfma_f32_32x32x16_f16(afrag, PA, zero16, 0, 0, 0); \
        f32x16 dvB = __builtin_amdgcn_mfma_f32_32x32x16_f16(afrag, PB, zero16, 0, 0, 0); \
        unsigned iv = ivb + (unsigned)((T) * 32);                              \
        float mm, kf;                                                          \
        mm = fminf(dvA[0],  dvB[0]);                                           \
        kf = __uint_as_float((__float_as_uint(mm) & HMASK) | iv); e0  = fminf(e0,  kf); \
        mm = fminf(dvA[1],  dvB[1]);                                           \
        kf = __uint_as_float((__float_as_uint(mm) & HMASK) | iv); e1  = fminf(e1,  kf); \
        mm = fminf(dvA[2],  dvB[2]);                                           \
        kf = __uint_as_float((__float_as_uint(mm) & HMASK) | iv); e2  = fminf(e2,  kf); \
        mm = fminf(dvA[3],  dvB[3]);                                           \
        kf = __uint_as_float((__float_as_uint(mm) & HMASK) | iv); e3  = fminf(e3,  kf); \
        mm = fminf(dvA[4],  dvB[4]);                                           \
        kf = __uint_as_float((__float_as_uint(mm) & HMASK) | iv); e4  = fminf(e4,  kf); \
        mm = fminf(dvA[5],  dvB[5]);                                           \
        kf = __uint_as_float((__float_as_uint(mm) & HMASK) | iv); e5  = fminf(e5,  kf); \
        mm = fminf(dvA[6],  dvB[6]);                                           \
        kf = __uint_as_float((__float_as_uint(mm) & HMASK) | iv); e6  = fminf(e6,  kf); \
        mm = fminf(dvA[7],  dvB[7]);                                           \
        kf = __uint_as_float((__float_as_uint(mm) & HMASK) | iv); e7  = fminf(e7,  kf); \
        mm = fminf(dvA[8],  dvB[8]);                                           \
        kf = __uint_as_float((__float_as_uint(mm) & HMASK) | iv); e8  = fminf(e8,  kf); \
        mm = fminf(dvA[9],  dvB[9]);                                           \
        kf = __uint_as_float((__float_as_uint(mm) & HMASK) | iv); e9  = fminf(e9,  kf); \
        mm = fminf(dvA[10], dvB[10]);                                          \
        kf = __uint_as_float((__float_as_uint(mm) & HMASK) | iv); e10 = fminf(e10, kf); \
        mm = fminf(dvA[11], dvB[11]);                                          \
        kf = __uint_as_float((__float_as_uint(mm) & HMASK) | iv); e11 = fminf(e11, kf); \
        mm = fminf(dvA[12], dvB[12]);                                          \
        kf = __uint_as_float((__float_as_uint(mm) & HMASK) | iv); e12 = fminf(e12, kf); \
        mm = fminf(dvA[13], dvB[13]);                                          \
        kf = __uint_as_float((__float_as_uint(mm) & HMASK) | iv); e13 = fminf(e13, kf); \
        mm = fminf(dvA[14], dvB[14]);                                          \
        kf = __uint_as_float((__float_as_uint(mm) & HMASK) | iv); e14 = fminf(e14, kf); \
        mm = fminf(dvA[15], dvB[15]);                                          \
        kf = __uint_as_float((__float_as_uint(mm) & HMASK) | iv); e15 = fminf(e15, kf); \
    }

    // 4-deep static ring prefetch, full unroll (R13 schedule, pairs inside)
    f16x8 p0 = LD(0), p1 = LD(1), p2 = LD(2), p3 = LD(3);
    #pragma unroll
    for (int t = 0; t < NT; t += 4) {
        f16x8 n0 = LD(t+4), n1 = LD(t+5);
        DOPAIR(p0, p1, t+0)
        f16x8 n2 = LD(t+6), n3 = LD(t+7);
        DOPAIR(p2, p3, t+2)
        p0 = n0; p1 = n1; p2 = n2; p3 = n3;
    }
#undef DOPAIR
#undef LD

    // dump 16 bins to LDS: bins[rowL][wv*32 + cls], rowL = ST-row + (lane>>5)*4
    {
        float* bb = &bins[((lane >> 5) * 4) * BSTR + wv * 32 + cls];
#define ST(RO, EG) bb[(RO) * BSTR] = EG;
        ST(0,e0)   ST(1,e1)   ST(2,e2)   ST(3,e3)
        ST(8,e4)   ST(9,e5)   ST(10,e6)  ST(11,e7)
        ST(16,e8)  ST(17,e9)  ST(18,e10) ST(19,e11)
        ST(24,e12) ST(25,e13) ST(26,e14) ST(27,e15)
#undef ST
    }
    __syncthreads();

    // ---- merge: wave wv owns rows 4wv..4wv+3; 16 lanes per row ----
    const int sr = lane >> 4;                // sub-row 0..3
    const int lr = lane & 15;                // lane within row group
    const int rl = wv * 4 + sr;              // row-local 0..31
    const int row = rowbase + rl;

    // per-lane top-2 over its 16 bins
    float g0 = FLT_MAX, g1 = FLT_MAX;
    #pragma unroll
    for (int i = 0; i < 16; ++i) {
        float v = bins[rl * BSTR + i * 16 + lr];
        g1 = MED3(g0, g1, v);
        g0 = fminf(g0, v);
    }

    // extract 8 smallest among the 16 lanes x top-2; lane s ends with s-th
    float kres = FLT_MAX;
    #pragma unroll
    for (int s = 0; s < KNN; ++s) {
        float m = g0;
        m = fminf(m, __shfl_xor(m, 1));
        m = fminf(m, __shfl_xor(m, 2));
        m = fminf(m, __shfl_xor(m, 4));
        m = fminf(m, __shfl_xor(m, 8));
        bool mine = (g0 == m);               // keys unique (idx in low bits)
        kres = (lr == s) ? m : kres;
        g0 = mine ? g1 : g0;
        g1 = mine ? FLT_MAX : g1;
    }

    if (lr < KNN)
        keys[((size_t)half * MPTS + row) * KNN + lr] = kres;   // sorted list
}

__global__ __launch_bounds__(128) void k_merge_loss(
    const float4* __restrict__ c4, const float* __restrict__ keys,
    const int* __restrict__ indice, const float* __restrict__ motion,
    const float* __restrict__ fdc, float* __restrict__ acc)
{
    __shared__ float rS[2], rM[2];
    const int tid  = threadIdx.x;
    const int lane = tid & 63;
    const int wv   = tid >> 6;
    const int row  = blockIdx.x * 128 + tid;

    // two sorted 8-lists (named regs; fully static)
    const float4* pa4 = (const float4*)(keys + (size_t)row * KNN);
    const float4* pb4 = (const float4*)(keys + ((size_t)MPTS + row) * KNN);
    float4 A0 = pa4[0], A1 = pa4[1], B0 = pb4[0], B1 = pb4[1];
    float a0=A0.x,a1=A0.y,a2=A0.z,a3=A0.w,a4=A1.x,a5=A1.y,a6=A1.z,a7=A1.w;
    float b0=B0.x,b1=B0.y,b2=B0.z,b3=B0.w,b4=B1.x,b5=B1.y,b6=B1.z,b7=B1.w;

    float4 rc = c4[row];
    const float qx=-0.5f*rc.x, qy=-0.5f*rc.y, qz=-0.5f*rc.z, qq=rc.w;
    const int irow = indice[row];
    const float f0 = fdc[3*irow+0], f1 = fdc[3*irow+1], f2 = fdc[3*irow+2];
    const float4* mr4 = (const float4*)(motion + CDIM * irow);
    float4 m0 = mr4[0], m1 = mr4[1], m2 = mr4[2], m3 = mr4[3];

    float sx = 0.f, sy = 0.f, sz = 0.f, simsum = 0.f;
    #pragma unroll
    for (int s = 0; s < KNN; ++s) {
        bool m = (a0 <= b0);
        float kk = m ? a0 : b0;
        // shift chosen list (all static-indexed)
        float na0=m?a1:a0, na1=m?a2:a1, na2=m?a3:a2, na3=m?a4:a3;
        float na4=m?a5:a4, na5=m?a6:a5, na6=m?a7:a6, na7=m?FLT_MAX:a7;
        float nb0=m?b0:b1, nb1=m?b1:b2, nb2=m?b2:b3, nb3=m?b3:b4;
        float nb4=m?b4:b5, nb5=m?b5:b6, nb6=m?b6:b7, nb7=m?b7:FLT_MAX;
        a0=na0;a1=na1;a2=na2;a3=na3;a4=na4;a5=na5;a6=na6;a7=na7;
        b0=nb0;b1=nb1;b2=nb2;b3=nb3;b4=nb4;b5=nb5;b6=nb6;b7=nb7;

        // resolve pair payload: candidates j0 and j0+32 (both exact f32,
        // loads independent -> issue in parallel)
        int j0 = (int)(__float_as_uint(kk) & 0x3FFFu);
        float4 n0 = c4[j0], n1 = c4[j0+32];
        float d0 = qq + fmaf(qx,n0.x, fmaf(qy,n0.y, fmaf(qz,n0.z, n0.w)));
        float d1 = qq + fmaf(qx,n1.x, fmaf(qy,n1.y, fmaf(qz,n1.z, n1.w)));
        bool sel = (d1 < d0);
        float d2k = sel ? d1 : d0;
        int jk = sel ? (j0 + 32) : j0;
        float4 nc; nc.x = sel?n1.x:n0.x; nc.y = sel?n1.y:n0.y;
        nc.z = sel?n1.z:n0.z; nc.w = sel?n1.w:n0.w;

        sx += -0.5f*nc.x; sy += -0.5f*nc.y; sz += -0.5f*nc.z;

        int inb = indice[jk];
        float c0v = f0 - fdc[3*inb+0] + EPSV;
        float c1v = f1 - fdc[3*inb+1] + EPSV;
        float c2v = f2 - fdc[3*inb+2] + EPSV;
        float cd2 = fmaf(c0v, c0v, fmaf(c1v, c1v, c2v * c2v));
        float w = __expf(-LAMW * fmaf(d2k, d2k, cd2));  // dist_w * color_w fused

        const float4* mn4 = (const float4*)(motion + CDIM * inb);
        float4 u0 = mn4[0], u1 = mn4[1], u2 = mn4[2], u3 = mn4[3];
        float sacc = 0.f;
#define MD(A,B) { float g0v=A.x-B.x+EPSV, g1v=A.y-B.y+EPSV,               \
                        g2v=A.z-B.z+EPSV, g3v=A.w-B.w+EPSV;               \
                  sacc = fmaf(g0v,g0v,fmaf(g1v,g1v,fmaf(g2v,g2v,fmaf(g3v,g3v,sacc)))); }
        MD(m0,u0) MD(m1,u1) MD(m2,u2) MD(m3,u3)
#undef MD
        simsum += w * sqrtf(sacc);
    }

    float dx = qx - sx * 0.125f + EPSV;
    float dy = qy - sy * 0.125f + EPSV;
    float dz = qz - sz * 0.125f + EPSV;
    float surf = sqrtf(fmaf(dx, dx, fmaf(dy, dy, dz * dz)));

    // ---- block reduction ----
    float aS = surf, aM = simsum;
    #pragma unroll
    for (int m = 1; m <= 32; m <<= 1) {
        aS += __shfl_xor(aS, m);
        aM += __shfl_xor(aM, m);
    }
    if (lane == 0) { rS[wv] = aS; rM[wv] = aM; }
    __syncthreads();
    if (tid == 0) {
        float tS = rS[0] + rS[1], tM = rM[0] + rM[1];
        atomicAdd(&acc[0], tS);
        atomicAdd(&acc[1], tM);
    }
}

__global__ void k_final(const float* __restrict__ acc, float* __restrict__ out)
{
    out[0] = acc[0] * (1.0f / MPTS) + acc[1] * (1.0f / (MPTS * KNN));
}

extern "C" void kernel_launch(void* const* d_in, const int* in_sizes, int n_in,
                              void* d_out, int out_size, void* d_ws, size_t ws_size,
                              hipStream_t stream)
{
    const float* canon  = (const float*)d_in[0];
    const float* trans  = (const float*)d_in[1];
    const float* motion = (const float*)d_in[2];
    const float* fdc    = (const float*)d_in[3];
    const int*   indice = (const int*)d_in[4];
    float* out = (float*)d_out;

    char* ws = (char*)d_ws;
    float*     acc   = (float*)ws;                          // @0
    float4*    c4    = (float4*)(ws + 4096);                // 256 KB
    _Float16*  af16b = (_Float16*)(ws + 4096 + 262144);     // 256 KB
    _Float16*  bf16b = (_Float16*)(ws + 4096 + 2*262144);   // 256 KB
    float*     keys  = (float*)(ws + 4096 + 3*262144);      // 2*M*8*4 = 1 MB

    k_gather<<<MPTS/256, 256, 0, stream>>>(canon, trans, indice, c4, bf16b, af16b, acc);
    k_knn<<<(MPTS/ROWS)*2, 512, 0, stream>>>(bf16b, af16b, keys);
    k_merge_loss<<<MPTS/128, 128, 0, stream>>>(c4, keys, indice, motion, fdc, acc);
    k_final<<<1, 1, 0, stream>>>(acc, out);
}

// Round 20
// 40.524 us; speedup vs baseline: 1.1387x; 1.1387x over previous
//
#include <hip/hip_runtime.h>
#include <hip/hip_bf16.h>
#include <float.h>

// RigidityLoss: M=16384 gathered points, brute-force KNN (K=8) + loss.
// R19 = R13/R17 (best known, 39.5 us) with k_final FUSED into k_merge_loss
// via last-block finalize (counter in acc[2], device-scope atomics) --
// removes one dispatch + inter-kernel gap. k_knn hot loop and merge inner
// loop are byte-identical to R17 (seven alternative restructures all
// regressed; those regions are closed).

#define MPTS 16384
#define KNN  8
#define CDIM 16
#define LAMW 0.1f
#define EPSV 1e-6f

#define ROWS   32              // rows per block (one 32x32 MFMA row-tile)
#define NSPLIT 8               // waves per block = candidate splits
#define CSPL   1024            // candidates per split (half / 8 waves)
#define NT     (CSPL/32)       // 32 MFMA tiles per wave
#define BSTR   257             // padded LDS bin-row stride (words)

#define MED3 __builtin_amdgcn_fmed3f
typedef __attribute__((ext_vector_type(8)))  _Float16 f16x8;
typedef __attribute__((ext_vector_type(16))) float    f32x16;

__global__ __launch_bounds__(256) void k_gather(
    const float* __restrict__ canon, const float* __restrict__ trans,
    const int* __restrict__ indice, float4* __restrict__ c4,
    _Float16* __restrict__ bf16b, _Float16* __restrict__ af16b,
    float* __restrict__ acc)
{
    int t = blockIdx.x * 256 + threadIdx.x;
    if (t == 0) { acc[0] = 0.f; acc[1] = 0.f; ((int*)acc)[2] = 0; }
    if (t < MPTS) {
        int j = indice[t];
        float x = canon[3*j+0] + trans[3*j+0];
        float y = canon[3*j+1] + trans[3*j+1];
        float z = canon[3*j+2] + trans[3*j+2];
        float sq = fmaf(x, x, fmaf(y, y, z*z));
        c4[t] = make_float4(-2.f*x, -2.f*y, -2.f*z, sq);   // exact f32 blob
        f16x8 aa = {};
        aa[0] = (_Float16)(-2.f*x); aa[1] = (_Float16)(-2.f*y);
        aa[2] = (_Float16)(-2.f*z); aa[3] = (_Float16)1.0f;
        *(f16x8*)(af16b + (size_t)t*8) = aa;
        f16x8 bb = {};
        bb[0] = (_Float16)x; bb[1] = (_Float16)y; bb[2] = (_Float16)z;
        bb[3] = (_Float16)sq;
        *(f16x8*)(bf16b + (size_t)t*8) = bb;
    }
}

__global__ __launch_bounds__(512, 4) void k_knn(
    const _Float16* __restrict__ bf16b, const _Float16* __restrict__ af16b,
    float* __restrict__ keys)
{
    __shared__ float bins[ROWS * BSTR];      // 32.9 KB

    const int tid  = threadIdx.x;
    const int lane = tid & 63;
    const int wv   = tid >> 6;               // wave = candidate split 0..7
    const int half = blockIdx.x & 1;
    const int rowbase = (blockIdx.x >> 1) * ROWS;
    const int cls  = lane & 31;
    const int cbeg = half * (MPTS/2) + wv * CSPL;

    // A fragment: lane l<32 -> row (rowbase+l), k=0..7; lanes>=32 (k=8..15) zero.
    f16x8 afrag = *(const f16x8*)(af16b + (size_t)(rowbase + cls) * 8);
    if (lane >= 32) { f16x8 zz = {}; afrag = zz; }
    f32x16 zero16 = {};

    const _Float16* bptr  = bf16b + (size_t)(cbeg + cls) * 8;
    const unsigned  HMASK = 0xFFFFC000u;
    const unsigned  ivb   = (unsigned)(cbeg + cls);

    // 16 row-states (g -> row (g&3)+8*(g>>2)+4*(lane>>5)), top-1 each
    float e0=FLT_MAX,e1=FLT_MAX,e2=FLT_MAX,e3=FLT_MAX;
    float e4=FLT_MAX,e5=FLT_MAX,e6=FLT_MAX,e7=FLT_MAX;
    float e8=FLT_MAX,e9=FLT_MAX,e10=FLT_MAX,e11=FLT_MAX;
    float e12=FLT_MAX,e13=FLT_MAX,e14=FLT_MAX,e15=FLT_MAX;

#define LD(T) (*(const f16x8*)(bptr + (size_t)(((T) & (NT-1)) * 256)))
#define DOTILE(PB, T)                                                          \
    {                                                                          \
        f32x16 dv = __builtin_amdgcn_mfma_f32_32x32x16_f16(afrag, PB, zero16, 0, 0, 0); \
        unsigned iv = ivb + (unsigned)((T) * 32);                              \
        float kf;                                                              \
        kf = __uint_as_float((__float_as_uint(dv[0])  & HMASK) | iv); e0  = fminf(e0,  kf); \
        kf = __uint_as_float((__float_as_uint(dv[1])  & HMASK) | iv); e1  = fminf(e1,  kf); \
        kf = __uint_as_float((__float_as_uint(dv[2])  & HMASK) | iv); e2  = fminf(e2,  kf); \
        kf = __uint_as_float((__float_as_uint(dv[3])  & HMASK) | iv); e3  = fminf(e3,  kf); \
        kf = __uint_as_float((__float_as_uint(dv[4])  & HMASK) | iv); e4  = fminf(e4,  kf); \
        kf = __uint_as_float((__float_as_uint(dv[5])  & HMASK) | iv); e5  = fminf(e5,  kf); \
        kf = __uint_as_float((__float_as_uint(dv[6])  & HMASK) | iv); e6  = fminf(e6,  kf); \
        kf = __uint_as_float((__float_as_uint(dv[7])  & HMASK) | iv); e7  = fminf(e7,  kf); \
        kf = __uint_as_float((__float_as_uint(dv[8])  & HMASK) | iv); e8  = fminf(e8,  kf); \
        kf = __uint_as_float((__float_as_uint(dv[9])  & HMASK) | iv); e9  = fminf(e9,  kf); \
        kf = __uint_as_float((__float_as_uint(dv[10]) & HMASK) | iv); e10 = fminf(e10, kf); \
        kf = __uint_as_float((__float_as_uint(dv[11]) & HMASK) | iv); e11 = fminf(e11, kf); \
        kf = __uint_as_float((__float_as_uint(dv[12]) & HMASK) | iv); e12 = fminf(e12, kf); \
        kf = __uint_as_float((__float_as_uint(dv[13]) & HMASK) | iv); e13 = fminf(e13, kf); \
        kf = __uint_as_float((__float_as_uint(dv[14]) & HMASK) | iv); e14 = fminf(e14, kf); \
        kf = __uint_as_float((__float_as_uint(dv[15]) & HMASK) | iv); e15 = fminf(e15, kf); \
    }

    // 4-deep static ring prefetch, FULL UNROLL (R13 best-known schedule)
    f16x8 p0 = LD(0), p1 = LD(1), p2 = LD(2), p3 = LD(3);
    #pragma unroll
    for (int t = 0; t < NT; t += 4) {
        f16x8 n0 = LD(t+4), n1 = LD(t+5);
        DOTILE(p0, t+0)
        DOTILE(p1, t+1)
        f16x8 n2 = LD(t+6), n3 = LD(t+7);
        DOTILE(p2, t+2)
        DOTILE(p3, t+3)
        p0 = n0; p1 = n1; p2 = n2; p3 = n3;
    }
#undef DOTILE
#undef LD

    // dump 16 bins to LDS: bins[rowL][wv*32 + cls], rowL = ST-row + (lane>>5)*4
    {
        float* bb = &bins[((lane >> 5) * 4) * BSTR + wv * 32 + cls];
#define ST(RO, EG) bb[(RO) * BSTR] = EG;
        ST(0,e0)   ST(1,e1)   ST(2,e2)   ST(3,e3)
        ST(8,e4)   ST(9,e5)   ST(10,e6)  ST(11,e7)
        ST(16,e8)  ST(17,e9)  ST(18,e10) ST(19,e11)
        ST(24,e12) ST(25,e13) ST(26,e14) ST(27,e15)
#undef ST
    }
    __syncthreads();

    // ---- merge: wave wv owns rows 4wv..4wv+3; 16 lanes per row ----
    const int sr = lane >> 4;                // sub-row 0..3
    const int lr = lane & 15;                // lane within row group
    const int rl = wv * 4 + sr;              // row-local 0..31
    const int row = rowbase + rl;

    // per-lane top-2 over its 16 bins
    float g0 = FLT_MAX, g1 = FLT_MAX;
    #pragma unroll
    for (int i = 0; i < 16; ++i) {
        float v = bins[rl * BSTR + i * 16 + lr];
        g1 = MED3(g0, g1, v);
        g0 = fminf(g0, v);
    }

    // extract 8 smallest among the 16 lanes x top-2; lane s ends with s-th
    float kres = FLT_MAX;
    #pragma unroll
    for (int s = 0; s < KNN; ++s) {
        float m = g0;
        m = fminf(m, __shfl_xor(m, 1));
        m = fminf(m, __shfl_xor(m, 2));
        m = fminf(m, __shfl_xor(m, 4));
        m = fminf(m, __shfl_xor(m, 8));
        bool mine = (g0 == m);               // keys unique (idx in low bits)
        kres = (lr == s) ? m : kres;
        g0 = mine ? g1 : g0;
        g1 = mine ? FLT_MAX : g1;
    }

    if (lr < KNN)
        keys[((size_t)half * MPTS + row) * KNN + lr] = kres;   // sorted list
}

__global__ __launch_bounds__(128) void k_merge_loss(
    const float4* __restrict__ c4, const float* __restrict__ keys,
    const int* __restrict__ indice, const float* __restrict__ motion,
    const float* __restrict__ fdc, float* __restrict__ acc,
    float* __restrict__ out)
{
    __shared__ float rS[2], rM[2];
    const int tid  = threadIdx.x;
    const int lane = tid & 63;
    const int wv   = tid >> 6;
    const int row  = blockIdx.x * 128 + tid;

    // two sorted 8-lists (named regs; fully static)
    const float4* pa4 = (const float4*)(keys + (size_t)row * KNN);
    const float4* pb4 = (const float4*)(keys + ((size_t)MPTS + row) * KNN);
    float4 A0 = pa4[0], A1 = pa4[1], B0 = pb4[0], B1 = pb4[1];
    float a0=A0.x,a1=A0.y,a2=A0.z,a3=A0.w,a4=A1.x,a5=A1.y,a6=A1.z,a7=A1.w;
    float b0=B0.x,b1=B0.y,b2=B0.z,b3=B0.w,b4=B1.x,b5=B1.y,b6=B1.z,b7=B1.w;

    float4 rc = c4[row];
    const float qx=-0.5f*rc.x, qy=-0.5f*rc.y, qz=-0.5f*rc.z, qq=rc.w;
    const int irow = indice[row];
    const float f0 = fdc[3*irow+0], f1 = fdc[3*irow+1], f2 = fdc[3*irow+2];
    const float4* mr4 = (const float4*)(motion + CDIM * irow);
    float4 m0 = mr4[0], m1 = mr4[1], m2 = mr4[2], m3 = mr4[3];

    float sx = 0.f, sy = 0.f, sz = 0.f, simsum = 0.f;
    #pragma unroll
    for (int s = 0; s < KNN; ++s) {
        bool m = (a0 <= b0);
        float kk = m ? a0 : b0;
        // shift chosen list (all static-indexed)
        float na0=m?a1:a0, na1=m?a2:a1, na2=m?a3:a2, na3=m?a4:a3;
        float na4=m?a5:a4, na5=m?a6:a5, na6=m?a7:a6, na7=m?FLT_MAX:a7;
        float nb0=m?b0:b1, nb1=m?b1:b2, nb2=m?b2:b3, nb3=m?b3:b4;
        float nb4=m?b4:b5, nb5=m?b5:b6, nb6=m?b6:b7, nb7=m?b7:FLT_MAX;
        a0=na0;a1=na1;a2=na2;a3=na3;a4=na4;a5=na5;a6=na6;a7=na7;
        b0=nb0;b1=nb1;b2=nb2;b3=nb3;b4=nb4;b5=nb5;b6=nb6;b7=nb7;

        int jk = (int)(__float_as_uint(kk) & 0x3FFFu);
        float4 nc = c4[jk];
        // exact squared distance (same expanded form as reference)
        float te  = fmaf(qx, nc.x, fmaf(qy, nc.y, fmaf(qz, nc.z, nc.w)));
        float d2k = qq + te;
        sx += -0.5f*nc.x; sy += -0.5f*nc.y; sz += -0.5f*nc.z;

        int inb = indice[jk];
        float c0v = f0 - fdc[3*inb+0] + EPSV;
        float c1v = f1 - fdc[3*inb+1] + EPSV;
        float c2v = f2 - fdc[3*inb+2] + EPSV;
        float cd2 = fmaf(c0v, c0v, fmaf(c1v, c1v, c2v * c2v));
        float w = __expf(-LAMW * fmaf(d2k, d2k, cd2));  // dist_w * color_w fused

        const float4* mn4 = (const float4*)(motion + CDIM * inb);
        float4 u0 = mn4[0], u1 = mn4[1], u2 = mn4[2], u3 = mn4[3];
        float sacc = 0.f;
#define MD(A,B) { float g0v=A.x-B.x+EPSV, g1v=A.y-B.y+EPSV,               \
                        g2v=A.z-B.z+EPSV, g3v=A.w-B.w+EPSV;               \
                  sacc = fmaf(g0v,g0v,fmaf(g1v,g1v,fmaf(g2v,g2v,fmaf(g3v,g3v,sacc)))); }
        MD(m0,u0) MD(m1,u1) MD(m2,u2) MD(m3,u3)
#undef MD
        simsum += w * sqrtf(sacc);
    }

    float dx = qx - sx * 0.125f + EPSV;
    float dy = qy - sy * 0.125f + EPSV;
    float dz = qz - sz * 0.125f + EPSV;
    float surf = sqrtf(fmaf(dx, dx, fmaf(dy, dy, dz * dz)));

    // ---- block reduction + last-block finalize ----
    float aS = surf, aM = simsum;
    #pragma unroll
    for (int m = 1; m <= 32; m <<= 1) {
        aS += __shfl_xor(aS, m);
        aM += __shfl_xor(aM, m);
    }
    if (lane == 0) { rS[wv] = aS; rM[wv] = aM; }
    __syncthreads();
    if (tid == 0) {
        float tS = rS[0] + rS[1], tM = rM[0] + rM[1];
        atomicAdd(&acc[0], tS);
        atomicAdd(&acc[1], tM);
        __threadfence();                          // publish before counting
        int done = atomicAdd((int*)&acc[2], 1);
        if (done == (int)gridDim.x - 1) {         // last block finalizes
            float s0 = atomicAdd(&acc[0], 0.f);   // device-scope coherent read
            float s1 = atomicAdd(&acc[1], 0.f);
            out[0] = s0 * (1.0f / MPTS) + s1 * (1.0f / (MPTS * KNN));
        }
    }
}

extern "C" void kernel_launch(void* const* d_in, const int* in_sizes, int n_in,
                              void* d_out, int out_size, void* d_ws, size_t ws_size,
                              hipStream_t stream)
{
    const float* canon  = (const float*)d_in[0];
    const float* trans  = (const float*)d_in[1];
    const float* motion = (const float*)d_in[2];
    const float* fdc    = (const float*)d_in[3];
    const int*   indice = (const int*)d_in[4];
    float* out = (float*)d_out;

    char* ws = (char*)d_ws;
    float*     acc   = (float*)ws;                          // @0 (2 sums + counter)
    float4*    c4    = (float4*)(ws + 4096);                // 256 KB
    _Float16*  af16b = (_Float16*)(ws + 4096 + 262144);     // 256 KB
    _Float16*  bf16b = (_Float16*)(ws + 4096 + 2*262144);   // 256 KB
    float*     keys  = (float*)(ws + 4096 + 3*262144);      // 2*M*8*4 = 1 MB

    k_gather<<<MPTS/256, 256, 0, stream>>>(canon, trans, indice, c4, bf16b, af16b, acc);
    k_knn<<<(MPTS/ROWS)*2, 512, 0, stream>>>(bf16b, af16b, keys);
    k_merge_loss<<<MPTS/128, 128, 0, stream>>>(c4, keys, indice, motion, fdc, acc, out);
}

// Round 21
// 39.721 us; speedup vs baseline: 1.1618x; 1.0202x over previous
//
#include <hip/hip_runtime.h>
#include <hip/hip_bf16.h>
#include <float.h>

// RigidityLoss: M=16384 gathered points, brute-force KNN (K=8) + loss.
// FINAL = R13/R17 (best known, 39.5-40.0 us across three independent runs):
//  k_gather: tp = canon+trans -> f32 blob (-2x,-2y,-2z,sq) + f16 A/B blobs
//            (A row = (-2x,-2y,-2z,1), B col = (x,y,z,sq)).
//  k_knn:    32x32x16 f16 MFMA computes shifted distance t = sq_c - 2*dot
//            directly (sq folded via k=3). Per-tile packed keys
//            (f32 dist high-bits | 14-bit cand idx) -> top-1 per
//            (row, cls, split) bin; 4-deep register prefetch ring, fully
//            unrolled; LDS bins -> 16-lane/row shfl extraction -> sorted
//            per-half top-8 lists.
//  k_merge_loss: exact two-pointer merge of the two sorted 8-lists per row
//            + loss terms with exact f32 d2 recompute; block-reduce + atomics.
//  k_final:  scalar finalize.
// Session ledger: 262 us (R0 naive) -> 39.5 us; eight alternative
// restructures of the hot loops all regressed or were neutral.

#define MPTS 16384
#define KNN  8
#define CDIM 16
#define LAMW 0.1f
#define EPSV 1e-6f

#define ROWS   32              // rows per block (one 32x32 MFMA row-tile)
#define NSPLIT 8               // waves per block = candidate splits
#define CSPL   1024            // candidates per split (half / 8 waves)
#define NT     (CSPL/32)       // 32 MFMA tiles per wave
#define BSTR   257             // padded LDS bin-row stride (words)

#define MED3 __builtin_amdgcn_fmed3f
typedef __attribute__((ext_vector_type(8)))  _Float16 f16x8;
typedef __attribute__((ext_vector_type(16))) float    f32x16;

__global__ __launch_bounds__(256) void k_gather(
    const float* __restrict__ canon, const float* __restrict__ trans,
    const int* __restrict__ indice, float4* __restrict__ c4,
    _Float16* __restrict__ bf16b, _Float16* __restrict__ af16b,
    float* __restrict__ acc)
{
    int t = blockIdx.x * 256 + threadIdx.x;
    if (t == 0) { acc[0] = 0.f; acc[1] = 0.f; }
    if (t < MPTS) {
        int j = indice[t];
        float x = canon[3*j+0] + trans[3*j+0];
        float y = canon[3*j+1] + trans[3*j+1];
        float z = canon[3*j+2] + trans[3*j+2];
        float sq = fmaf(x, x, fmaf(y, y, z*z));
        c4[t] = make_float4(-2.f*x, -2.f*y, -2.f*z, sq);   // exact f32 blob
        f16x8 aa = {};
        aa[0] = (_Float16)(-2.f*x); aa[1] = (_Float16)(-2.f*y);
        aa[2] = (_Float16)(-2.f*z); aa[3] = (_Float16)1.0f;
        *(f16x8*)(af16b + (size_t)t*8) = aa;
        f16x8 bb = {};
        bb[0] = (_Float16)x; bb[1] = (_Float16)y; bb[2] = (_Float16)z;
        bb[3] = (_Float16)sq;
        *(f16x8*)(bf16b + (size_t)t*8) = bb;
    }
}

__global__ __launch_bounds__(512, 4) void k_knn(
    const _Float16* __restrict__ bf16b, const _Float16* __restrict__ af16b,
    float* __restrict__ keys)
{
    __shared__ float bins[ROWS * BSTR];      // 32.9 KB

    const int tid  = threadIdx.x;
    const int lane = tid & 63;
    const int wv   = tid >> 6;               // wave = candidate split 0..7
    const int half = blockIdx.x & 1;
    const int rowbase = (blockIdx.x >> 1) * ROWS;
    const int cls  = lane & 31;
    const int cbeg = half * (MPTS/2) + wv * CSPL;

    // A fragment: lane l<32 -> row (rowbase+l), k=0..7; lanes>=32 (k=8..15) zero.
    f16x8 afrag = *(const f16x8*)(af16b + (size_t)(rowbase + cls) * 8);
    if (lane >= 32) { f16x8 zz = {}; afrag = zz; }
    f32x16 zero16 = {};

    const _Float16* bptr  = bf16b + (size_t)(cbeg + cls) * 8;
    const unsigned  HMASK = 0xFFFFC000u;
    const unsigned  ivb   = (unsigned)(cbeg + cls);

    // 16 row-states (g -> row (g&3)+8*(g>>2)+4*(lane>>5)), top-1 each
    float e0=FLT_MAX,e1=FLT_MAX,e2=FLT_MAX,e3=FLT_MAX;
    float e4=FLT_MAX,e5=FLT_MAX,e6=FLT_MAX,e7=FLT_MAX;
    float e8=FLT_MAX,e9=FLT_MAX,e10=FLT_MAX,e11=FLT_MAX;
    float e12=FLT_MAX,e13=FLT_MAX,e14=FLT_MAX,e15=FLT_MAX;

#define LD(T) (*(const f16x8*)(bptr + (size_t)(((T) & (NT-1)) * 256)))
#define DOTILE(PB, T)                                                          \
    {                                                                          \
        f32x16 dv = __builtin_amdgcn_mfma_f32_32x32x16_f16(afrag, PB, zero16, 0, 0, 0); \
        unsigned iv = ivb + (unsigned)((T) * 32);                              \
        float kf;                                                              \
        kf = __uint_as_float((__float_as_uint(dv[0])  & HMASK) | iv); e0  = fminf(e0,  kf); \
        kf = __uint_as_float((__float_as_uint(dv[1])  & HMASK) | iv); e1  = fminf(e1,  kf); \
        kf = __uint_as_float((__float_as_uint(dv[2])  & HMASK) | iv); e2  = fminf(e2,  kf); \
        kf = __uint_as_float((__float_as_uint(dv[3])  & HMASK) | iv); e3  = fminf(e3,  kf); \
        kf = __uint_as_float((__float_as_uint(dv[4])  & HMASK) | iv); e4  = fminf(e4,  kf); \
        kf = __uint_as_float((__float_as_uint(dv[5])  & HMASK) | iv); e5  = fminf(e5,  kf); \
        kf = __uint_as_float((__float_as_uint(dv[6])  & HMASK) | iv); e6  = fminf(e6,  kf); \
        kf = __uint_as_float((__float_as_uint(dv[7])  & HMASK) | iv); e7  = fminf(e7,  kf); \
        kf = __uint_as_float((__float_as_uint(dv[8])  & HMASK) | iv); e8  = fminf(e8,  kf); \
        kf = __uint_as_float((__float_as_uint(dv[9])  & HMASK) | iv); e9  = fminf(e9,  kf); \
        kf = __uint_as_float((__float_as_uint(dv[10]) & HMASK) | iv); e10 = fminf(e10, kf); \
        kf = __uint_as_float((__float_as_uint(dv[11]) & HMASK) | iv); e11 = fminf(e11, kf); \
        kf = __uint_as_float((__float_as_uint(dv[12]) & HMASK) | iv); e12 = fminf(e12, kf); \
        kf = __uint_as_float((__float_as_uint(dv[13]) & HMASK) | iv); e13 = fminf(e13, kf); \
        kf = __uint_as_float((__float_as_uint(dv[14]) & HMASK) | iv); e14 = fminf(e14, kf); \
        kf = __uint_as_float((__float_as_uint(dv[15]) & HMASK) | iv); e15 = fminf(e15, kf); \
    }

    // 4-deep static ring prefetch, FULL UNROLL (best-known schedule)
    f16x8 p0 = LD(0), p1 = LD(1), p2 = LD(2), p3 = LD(3);
    #pragma unroll
    for (int t = 0; t < NT; t += 4) {
        f16x8 n0 = LD(t+4), n1 = LD(t+5);
        DOTILE(p0, t+0)
        DOTILE(p1, t+1)
        f16x8 n2 = LD(t+6), n3 = LD(t+7);
        DOTILE(p2, t+2)
        DOTILE(p3, t+3)
        p0 = n0; p1 = n1; p2 = n2; p3 = n3;
    }
#undef DOTILE
#undef LD

    // dump 16 bins to LDS: bins[rowL][wv*32 + cls], rowL = ST-row + (lane>>5)*4
    {
        float* bb = &bins[((lane >> 5) * 4) * BSTR + wv * 32 + cls];
#define ST(RO, EG) bb[(RO) * BSTR] = EG;
        ST(0,e0)   ST(1,e1)   ST(2,e2)   ST(3,e3)
        ST(8,e4)   ST(9,e5)   ST(10,e6)  ST(11,e7)
        ST(16,e8)  ST(17,e9)  ST(18,e10) ST(19,e11)
        ST(24,e12) ST(25,e13) ST(26,e14) ST(27,e15)
#undef ST
    }
    __syncthreads();

    // ---- merge: wave wv owns rows 4wv..4wv+3; 16 lanes per row ----
    const int sr = lane >> 4;                // sub-row 0..3
    const int lr = lane & 15;                // lane within row group
    const int rl = wv * 4 + sr;              // row-local 0..31
    const int row = rowbase + rl;

    // per-lane top-2 over its 16 bins
    float g0 = FLT_MAX, g1 = FLT_MAX;
    #pragma unroll
    for (int i = 0; i < 16; ++i) {
        float v = bins[rl * BSTR + i * 16 + lr];
        g1 = MED3(g0, g1, v);
        g0 = fminf(g0, v);
    }

    // extract 8 smallest among the 16 lanes x top-2; lane s ends with s-th
    float kres = FLT_MAX;
    #pragma unroll
    for (int s = 0; s < KNN; ++s) {
        float m = g0;
        m = fminf(m, __shfl_xor(m, 1));
        m = fminf(m, __shfl_xor(m, 2));
        m = fminf(m, __shfl_xor(m, 4));
        m = fminf(m, __shfl_xor(m, 8));
        bool mine = (g0 == m);               // keys unique (idx in low bits)
        kres = (lr == s) ? m : kres;
        g0 = mine ? g1 : g0;
        g1 = mine ? FLT_MAX : g1;
    }

    if (lr < KNN)
        keys[((size_t)half * MPTS + row) * KNN + lr] = kres;   // sorted list
}

__global__ __launch_bounds__(128) void k_merge_loss(
    const float4* __restrict__ c4, const float* __restrict__ keys,
    const int* __restrict__ indice, const float* __restrict__ motion,
    const float* __restrict__ fdc, float* __restrict__ acc)
{
    __shared__ float rS[2], rM[2];
    const int tid  = threadIdx.x;
    const int lane = tid & 63;
    const int wv   = tid >> 6;
    const int row  = blockIdx.x * 128 + tid;

    // two sorted 8-lists (named regs; fully static)
    const float4* pa4 = (const float4*)(keys + (size_t)row * KNN);
    const float4* pb4 = (const float4*)(keys + ((size_t)MPTS + row) * KNN);
    float4 A0 = pa4[0], A1 = pa4[1], B0 = pb4[0], B1 = pb4[1];
    float a0=A0.x,a1=A0.y,a2=A0.z,a3=A0.w,a4=A1.x,a5=A1.y,a6=A1.z,a7=A1.w;
    float b0=B0.x,b1=B0.y,b2=B0.z,b3=B0.w,b4=B1.x,b5=B1.y,b6=B1.z,b7=B1.w;

    float4 rc = c4[row];
    const float qx=-0.5f*rc.x, qy=-0.5f*rc.y, qz=-0.5f*rc.z, qq=rc.w;
    const int irow = indice[row];
    const float f0 = fdc[3*irow+0], f1 = fdc[3*irow+1], f2 = fdc[3*irow+2];
    const float4* mr4 = (const float4*)(motion + CDIM * irow);
    float4 m0 = mr4[0], m1 = mr4[1], m2 = mr4[2], m3 = mr4[3];

    float sx = 0.f, sy = 0.f, sz = 0.f, simsum = 0.f;
    #pragma unroll
    for (int s = 0; s < KNN; ++s) {
        bool m = (a0 <= b0);
        float kk = m ? a0 : b0;
        // shift chosen list (all static-indexed)
        float na0=m?a1:a0, na1=m?a2:a1, na2=m?a3:a2, na3=m?a4:a3;
        float na4=m?a5:a4, na5=m?a6:a5, na6=m?a7:a6, na7=m?FLT_MAX:a7;
        float nb0=m?b0:b1, nb1=m?b1:b2, nb2=m?b2:b3, nb3=m?b3:b4;
        float nb4=m?b4:b5, nb5=m?b5:b6, nb6=m?b6:b7, nb7=m?b7:FLT_MAX;
        a0=na0;a1=na1;a2=na2;a3=na3;a4=na4;a5=na5;a6=na6;a7=na7;
        b0=nb0;b1=nb1;b2=nb2;b3=nb3;b4=nb4;b5=nb5;b6=nb6;b7=nb7;

        int jk = (int)(__float_as_uint(kk) & 0x3FFFu);
        float4 nc = c4[jk];
        // exact squared distance (same expanded form as reference)
        float te  = fmaf(qx, nc.x, fmaf(qy, nc.y, fmaf(qz, nc.z, nc.w)));
        float d2k = qq + te;
        sx += -0.5f*nc.x; sy += -0.5f*nc.y; sz += -0.5f*nc.z;

        int inb = indice[jk];
        float c0v = f0 - fdc[3*inb+0] + EPSV;
        float c1v = f1 - fdc[3*inb+1] + EPSV;
        float c2v = f2 - fdc[3*inb+2] + EPSV;
        float cd2 = fmaf(c0v, c0v, fmaf(c1v, c1v, c2v * c2v));
        float w = __expf(-LAMW * fmaf(d2k, d2k, cd2));  // dist_w * color_w fused

        const float4* mn4 = (const float4*)(motion + CDIM * inb);
        float4 u0 = mn4[0], u1 = mn4[1], u2 = mn4[2], u3 = mn4[3];
        float sacc = 0.f;
#define MD(A,B) { float g0v=A.x-B.x+EPSV, g1v=A.y-B.y+EPSV,               \
                        g2v=A.z-B.z+EPSV, g3v=A.w-B.w+EPSV;               \
                  sacc = fmaf(g0v,g0v,fmaf(g1v,g1v,fmaf(g2v,g2v,fmaf(g3v,g3v,sacc)))); }
        MD(m0,u0) MD(m1,u1) MD(m2,u2) MD(m3,u3)
#undef MD
        simsum += w * sqrtf(sacc);
    }

    float dx = qx - sx * 0.125f + EPSV;
    float dy = qy - sy * 0.125f + EPSV;
    float dz = qz - sz * 0.125f + EPSV;
    float surf = sqrtf(fmaf(dx, dx, fmaf(dy, dy, dz * dz)));

    // ---- block reduction ----
    float aS = surf, aM = simsum;
    #pragma unroll
    for (int m = 1; m <= 32; m <<= 1) {
        aS += __shfl_xor(aS, m);
        aM += __shfl_xor(aM, m);
    }
    if (lane == 0) { rS[wv] = aS; rM[wv] = aM; }
    __syncthreads();
    if (tid == 0) {
        float tS = rS[0] + rS[1], tM = rM[0] + rM[1];
        atomicAdd(&acc[0], tS);
        atomicAdd(&acc[1], tM);
    }
}

__global__ void k_final(const float* __restrict__ acc, float* __restrict__ out)
{
    out[0] = acc[0] * (1.0f / MPTS) + acc[1] * (1.0f / (MPTS * KNN));
}

extern "C" void kernel_launch(void* const* d_in, const int* in_sizes, int n_in,
                              void* d_out, int out_size, void* d_ws, size_t ws_size,
                              hipStream_t stream)
{
    const float* canon  = (const float*)d_in[0];
    const float* trans  = (const float*)d_in[1];
    const float* motion = (const float*)d_in[2];
    const float* fdc    = (const float*)d_in[3];
    const int*   indice = (const int*)d_in[4];
    float* out = (float*)d_out;

    char* ws = (char*)d_ws;
    float*     acc   = (float*)ws;                          // @0
    float4*    c4    = (float4*)(ws + 4096);                // 256 KB
    _Float16*  af16b = (_Float16*)(ws + 4096 + 262144);     // 256 KB
    _Float16*  bf16b = (_Float16*)(ws + 4096 + 2*262144);   // 256 KB
    float*     keys  = (float*)(ws + 4096 + 3*262144);      // 2*M*8*4 = 1 MB

    k_gather<<<MPTS/256, 256, 0, stream>>>(canon, trans, indice, c4, bf16b, af16b, acc);
    k_knn<<<(MPTS/ROWS)*2, 512, 0, stream>>>(bf16b, af16b, keys);
    k_merge_loss<<<MPTS/128, 128, 0, stream>>>(c4, keys, indice, motion, fdc, acc);
    k_final<<<1, 1, 0, stream>>>(acc, out);
}